// Round 1
// 417.922 us; speedup vs baseline: 1.0178x; 1.0178x over previous
//
#include <hip/hip_runtime.h>
#include <hip/hip_bf16.h>

#define BS_   2048
#define HID_  512
#define PH_   32
#define GRP_  16        // blocks per sync group

typedef _Float16 half8 __attribute__((ext_vector_type(8)));
typedef float floatx4 __attribute__((ext_vector_type(4)));

__device__ __forceinline__ float sigf(float x) { return 1.f / (1.f + __expf(-x)); }
__device__ __forceinline__ float tanhfast(float x) {
    float e = __expf(2.f * x);          // e=inf -> 1, e->0 -> -1 : safe at extremes
    return 1.f - 2.f / (e + 1.f);
}

// ---------------------------------------------------------------------------
// Prep: fp16 weights (W_ih, W_ih+W_hh), combined bias, z16, zero the step
// counters (16 groups x 32 slots; slots 0..30 = step signals, slot 31 = the
// one-time XCD handshake word for that group).
// ---------------------------------------------------------------------------
__global__ __launch_bounds__(256) void prep_kernel(
    const float* __restrict__ Wih, const float* __restrict__ Whh,
    const float* __restrict__ bih, const float* __restrict__ bhh,
    const float* __restrict__ z,
    _Float16* __restrict__ wih16, _Float16* __restrict__ wsum16,
    _Float16* __restrict__ z16, float* __restrict__ bsum,
    int* __restrict__ cnt)
{
    int i = blockIdx.x * 256 + threadIdx.x;          // [0, 1048576)
    if (i < BS_ * HID_) z16[i] = (_Float16)z[i];
    if (i < 4 * HID_ * HID_) {
        float a = Wih[i];
        wih16[i]  = (_Float16)a;
        wsum16[i] = (_Float16)(a + Whh[i]);
    }
    if (i < 4 * HID_) bsum[i] = bih[i] + bhh[i];
    if (i < 512) cnt[i] = 0;
}

// ---------------------------------------------------------------------------
// Stage a 32-hid weight slice: 128 gate rows x 512 K fp16 = 128 KB LDS,
// XOR-swizzled on 16B blocks (row&7 == ln&7 at read time, conflict-free).
// ---------------------------------------------------------------------------
__device__ __forceinline__ void stage_weights(_Float16* Wl, const _Float16* Wg,
                                              int j, int tid)
{
#pragma unroll
    for (int rep = 0; rep < 16; ++rep) {
        int idx = rep * 512 + tid;      // [0, 8192): row n in [0,128), kb in [0,64)
        int n  = idx >> 6;
        int kb = idx & 63;
        int g  = n >> 5, u = n & 31;    // gate, hid-within-slice
        const half8* src = (const half8*)(Wg + ((size_t)(g * HID_ + j * 32 + u)) * HID_ + kb * 8);
        int phys = (kb & 56) | ((kb & 7) ^ (n & 7));
        *(half8*)((char*)Wl + n * 1024 + phys * 16) = *src;
    }
}

// ---------------------------------------------------------------------------
// Persistent LSTM, R6-proven block-level protocol, GROUP SIZE 16.
// Grid = 256 x 512. ib = blockIdx & 15 (128-row batch tile), j = blockIdx>>4
// (32 hid units = 128 gate rows, 128 KB LDS). Wave wv: M-strip (wv&3)*32
// rows, hid-half wv>>2 (0.5 B-reads/MFMA, all 4 gates in-thread).
//
// NEW (this round): the 16 blocks of a group are {ib + 16k}; 16 == 0 mod 8,
// so under round-robin blockIdx->XCD placement the whole group shares one
// XCD (and its L2). A one-time handshake verifies this at runtime via
// HW_REG_XCC_ID packed into cnt[ib*32+31] (low byte = arrival count, bits
// 8.. = XCD bitmask). If the verdict is "one XCD", h stores use plain
// write-back (data stays in the shared per-XCD L2; consumers' loads are L2
// hits instead of LLC round trips). L1 staleness is impossible: L1 is
// write-through, every step reads fresh addresses, and dispatch-level
// acquire invalidates L1 across bench replays. If the group spans XCDs the
// R6 agent-scope write-through path is used unchanged (correctness never
// depends on the dispatch mapping). Signal counters stay agent-scope RMW
// either way. Per-wave protocol variants regressed 4-5x (R7/R8) -- do not
// re-attempt.
// ---------------------------------------------------------------------------
__global__ __launch_bounds__(512) void lstm_persist(
    const _Float16* __restrict__ wih16, const _Float16* __restrict__ wsum16,
    const float* __restrict__ bsum, const _Float16* __restrict__ z16,
    _Float16* __restrict__ hs, int* __restrict__ cnt)
{
    __shared__ _Float16 Wl[128 * 512];   // 128 KB

    const int tid  = threadIdx.x;
    const int ib   = blockIdx.x & 15;
    const int j    = blockIdx.x >> 4;
    const int lane = tid & 63;
    const int wv   = tid >> 6;
    const int ms   = wv & 3;            // M-strip: 32 rows of the 128-row tile
    const int hh   = wv >> 2;           // hid half: 0 -> units 0..15, 1 -> 16..31
    const int qw   = lane >> 4;         // quad 0..3
    const int ln   = lane & 15;
    const int hid  = j * 32 + hh * 16 + ln;

    stage_weights(Wl, wih16, j, tid);

    // --- one-time group XCD handshake (slot 31 of this group's counters) ---
    if (tid == 0) {
        unsigned xcc = 0;
        asm volatile("s_getreg_b32 %0, hwreg(HW_REG_XCC_ID)" : "=s"(xcc));
        int bit = 1 << (8 + (int)(xcc & 15));
        __hip_atomic_fetch_or(&cnt[ib * 32 + 31], bit,
                              __ATOMIC_RELAXED, __HIP_MEMORY_SCOPE_AGENT);
        __hip_atomic_fetch_add(&cnt[ib * 32 + 31], 1,
                               __ATOMIC_RELAXED, __HIP_MEMORY_SCOPE_AGENT);
        while ((__hip_atomic_fetch_add(&cnt[ib * 32 + 31], 0,
                                       __ATOMIC_RELAXED,
                                       __HIP_MEMORY_SCOPE_AGENT) & 0xff) < GRP_) {
            __builtin_amdgcn_s_sleep(1);
        }
    }

    float bias[4];
#pragma unroll
    for (int g = 0; g < 4; ++g) bias[g] = bsum[g * HID_ + hid];

    float c[2][4];
#pragma unroll
    for (int mt = 0; mt < 2; ++mt)
#pragma unroll
        for (int r = 0; r < 4; ++r) c[mt][r] = 0.f;

    const char* Bl = (const char*)Wl;
    const int tE = (qw ^ (ln & 7)) * 16;    // swizzled byte offset, kk-even
    const int rowB = hh * 16 + ln;          // LDS row within a gate's 32 rows

    __syncthreads();    // staging complete AND handshake word final

    // value is final after count==16 (exactly 16 publishes, monotone word)
    const int hsk = __hip_atomic_load(&cnt[ib * 32 + 31], __ATOMIC_RELAXED,
                                      __HIP_MEMORY_SCOPE_AGENT);
    const bool fastp = __popc(((unsigned)hsk) >> 8) == 1;   // group on one XCD

    for (int t = 0; t < PH_; ++t) {
        const _Float16* xx = (t == 0) ? z16 : hs + (size_t)(t - 1) * BS_ * HID_;

        if (t >= 1) {
            if (tid == 0) {
                while (__hip_atomic_fetch_add(&cnt[ib * 32 + t - 1], 0,
                                              __ATOMIC_RELAXED,
                                              __HIP_MEMORY_SCOPE_AGENT) < GRP_) {
                    __builtin_amdgcn_s_sleep(1);
                }
            }
            __syncthreads();    // orders all following loads after the poll
        }

        floatx4 acc[2][4];                  // bias pre-folded
#pragma unroll
        for (int mt = 0; mt < 2; ++mt)
#pragma unroll
            for (int g = 0; g < 4; ++g)
                acc[mt][g] = (floatx4){bias[g], bias[g], bias[g], bias[g]};

        // A fragment: A[m = ln][k = qw*8 + jj]; depth-4 global prefetch ring
        const _Float16* A0 = xx + (size_t)(ib * 128 + ms * 32 + ln) * HID_ + qw * 8;

        half8 a0r[4], a1r[4], bA[4], bB[4];
#pragma unroll
        for (int p = 0; p < 4; ++p) {
            a0r[p] = *(const half8*)(A0 + p * 32);
            a1r[p] = *(const half8*)(A0 + 16 * HID_ + p * 32);
        }
#pragma unroll
        for (int g = 0; g < 4; ++g)
            bA[g] = *(const half8*)(Bl + (g * 32 + rowB) * 1024 + tE);

#pragma unroll
        for (int kk = 0; kk < 16; ++kk) {
            half8 ca0 = a0r[kk & 3], ca1 = a1r[kk & 3];
            if (kk < 12) {
                a0r[kk & 3] = *(const half8*)(A0 + (kk + 4) * 32);
                a1r[kk & 3] = *(const half8*)(A0 + 16 * HID_ + (kk + 4) * 32);
            }
            half8* cb = (kk & 1) ? bB : bA;
            half8* nb = (kk & 1) ? bA : bB;
            if (kk < 15) {
                int k1 = kk + 1;
#pragma unroll
                for (int g = 0; g < 4; ++g) {
                    int off = (g * 32 + rowB) * 1024 + (k1 >> 1) * 128 + (tE ^ ((k1 & 1) << 6));
                    nb[g] = *(const half8*)(Bl + off);
                }
            }
#pragma unroll
            for (int g = 0; g < 4; ++g) {
                acc[0][g] = __builtin_amdgcn_mfma_f32_16x16x32_f16(ca0, cb[g], acc[0][g], 0, 0, 0);
                acc[1][g] = __builtin_amdgcn_mfma_f32_16x16x32_f16(ca1, cb[g], acc[1][g], 0, 0, 0);
            }
        }

        // epilogue: C/D layout col=ln, row=qw*4+r; all 4 gates in-thread.
        _Float16* hb = hs + (size_t)t * BS_ * HID_
                          + (size_t)(ib * 128 + ms * 32 + qw * 4) * HID_ + hid;
        short hvv[2][4];
#pragma unroll
        for (int mt = 0; mt < 2; ++mt) {
#pragma unroll
            for (int r = 0; r < 4; ++r) {
                float gi = acc[mt][0][r];
                float gf = acc[mt][1][r];
                float gg = acc[mt][2][r];
                float go = acc[mt][3][r];
                float cn = sigf(gf) * c[mt][r] + sigf(gi) * tanhfast(gg);
                float hn = sigf(go) * tanhfast(cn);
                c[mt][r] = cn;
                _Float16 hf = (_Float16)hn;
                __builtin_memcpy(&hvv[mt][r], &hf, 2);
            }
        }
        if (fastp) {
            // same-XCD group: plain write-back stores; __syncthreads drains
            // vmcnt => stores acked at the shared L2 before tid0 signals.
#pragma unroll
            for (int mt = 0; mt < 2; ++mt)
#pragma unroll
                for (int r = 0; r < 4; ++r)
                    *(short*)(hb + (size_t)(mt * 16 + r) * HID_) = hvv[mt][r];
        } else {
            // cross-XCD fallback: R6 agent-scope write-through (LLC).
#pragma unroll
            for (int mt = 0; mt < 2; ++mt)
#pragma unroll
                for (int r = 0; r < 4; ++r)
                    __hip_atomic_store((short*)(hb + (size_t)(mt * 16 + r) * HID_),
                                       hvv[mt][r],
                                       __ATOMIC_RELAXED, __HIP_MEMORY_SCOPE_AGENT);
        }

        // Barrier drains every wave's stores (vmcnt(0)), then ONE relaxed
        // CP-RMW signals the group.
        __syncthreads();
        if (t == 0) {
            if (tid == 0)
                __hip_atomic_fetch_add(&cnt[ib * 32], 1,
                                       __ATOMIC_RELAXED, __HIP_MEMORY_SCOPE_AGENT);
            stage_weights(Wl, wsum16, j, tid);   // switch to W_ih+W_hh (once)
            __syncthreads();
        } else if (t < PH_ - 1) {
            if (tid == 0)
                __hip_atomic_fetch_add(&cnt[ib * 32 + t], 1,
                                       __ATOMIC_RELAXED, __HIP_MEMORY_SCOPE_AGENT);
        }
    }
}

// ---------------------------------------------------------------------------
// y[b,t,:] = hs[t][b,:] @ W_d^T + b_d. Wd staged once per block (4 KB LDS ->
// registers); each wave handles 8 rows. Old version re-read Wd from global
// per wave (65536 waves x 4 KB = 256 MB of redundant L2/LLC traffic); now
// Wd traffic is 2048 x 4 KB = 8 MB and the kernel is HBM-bound on hs.
// ---------------------------------------------------------------------------
__global__ __launch_bounds__(256) void dense_kernel(
    const _Float16* __restrict__ hs, const float* __restrict__ Wd,
    const float* __restrict__ bd, float* __restrict__ y)
{
    __shared__ float4 WdL4[256];        // 1024 floats = Wd (2 x 512)
    const int tid = threadIdx.x;
    WdL4[tid] = ((const float4*)Wd)[tid];
    __syncthreads();
    const float* WdL = (const float*)WdL4;

    const int lane = tid & 63;
    const int wv   = tid >> 6;          // wave in block, 0..3
    float wd0[8], wd1[8];
#pragma unroll
    for (int k = 0; k < 8; ++k) {
        wd0[k] = WdL[lane * 8 + k];
        wd1[k] = WdL[HID_ + lane * 8 + k];
    }
    const float b0 = bd[0], b1 = bd[1];

    const int base = (blockIdx.x * 4 + wv) * 8;   // 8 rows per wave
#pragma unroll
    for (int i = 0; i < 8; ++i) {
        const int r  = base + i;                  // [0, 65536)
        const int tt = r & 31, b = r >> 5;
        half8 h = *(const half8*)(hs + ((size_t)tt * BS_ + b) * HID_ + lane * 8);
        float s0 = 0.f, s1 = 0.f;
#pragma unroll
        for (int k = 0; k < 8; ++k) {
            float hv = (float)h[k];
            s0 += hv * wd0[k];
            s1 += hv * wd1[k];
        }
#pragma unroll
        for (int m = 32; m >= 1; m >>= 1) {
            s0 += __shfl_xor(s0, m);
            s1 += __shfl_xor(s1, m);
        }
        if (lane == 0) {
            float* o = y + ((size_t)b * PH_ + tt) * 2;
            o[0] = s0 + b0;
            o[1] = s1 + b1;
        }
    }
}

// ---------------------------------------------------------------------------
extern "C" void kernel_launch(void* const* d_in, const int* in_sizes, int n_in,
                              void* d_out, int out_size, void* d_ws, size_t ws_size,
                              hipStream_t stream)
{
    (void)in_sizes; (void)n_in; (void)out_size; (void)ws_size;
    // setup_inputs order: hist(0, unused), z(1), W_ih(2), W_hh(3), b_ih(4),
    //                     b_hh(5), W_d(6), b_d(7)
    const float* z   = (const float*)d_in[1];
    const float* Wih = (const float*)d_in[2];
    const float* Whh = (const float*)d_in[3];
    const float* bih = (const float*)d_in[4];
    const float* bhh = (const float*)d_in[5];
    const float* Wd  = (const float*)d_in[6];
    const float* bd  = (const float*)d_in[7];
    float* y = (float*)d_out;

    char* ws = (char*)d_ws;
    _Float16* hs     = (_Float16*)ws;                          // 32*2048*512*2 = 64 MB
    _Float16* z16    = (_Float16*)(ws + (size_t)67108864);     // 2 MB
    _Float16* wih16  = (_Float16*)(ws + (size_t)69206016);     // 2 MB
    _Float16* wsum16 = (_Float16*)(ws + (size_t)71303168);     // 2 MB
    float*    bsum   = (float*)   (ws + (size_t)73400320);     // 8 KB
    int*      cnt    = (int*)     (ws + (size_t)73408512);     // 512 ints

    prep_kernel<<<4096, 256, 0, stream>>>(Wih, Whh, bih, bhh, z,
                                          wih16, wsum16, z16, bsum, cnt);

    {
        const void* k = (const void*)lstm_persist;
        void* args[] = {(void*)&wih16, (void*)&wsum16, (void*)&bsum,
                        (void*)&z16, (void*)&hs, (void*)&cnt};
        hipLaunchCooperativeKernel(k, dim3(256), dim3(512), args, 0, stream);
    }

    dense_kernel<<<2048, 256, 0, stream>>>(hs, Wd, bd, y);
}